// Round 10
// baseline (320.155 us; speedup 1.0000x reference)
//
#include <hip/hip_runtime.h>
#include <hip/hip_bf16.h>
#include <math.h>
#include <type_traits>

// ---------------------------------------------------------------------------
// SelfAttention B=4,T=2048,D=1024 fp32 in/out.
// Round 20: acc[4][4] wave-tile 128x128 -- fix the FEED RATIO, not the feed.
//   R13-R19 audit: every variant was feed-bound at ~30% MfmaUtil because
//   bytes-into-CU per MFMA-cycle exceeded the port budget:
//     acc[2][2] LDS: 128 B/cy vs 85 | acc[4][2] LDS: 96 vs 85 |
//     acc[2][2] direct-L2 (R19): 128 vs 56.
//   acc[4][4] halves demand: per K=16 step a wave runs 16 MFMAs (512 cy on
//   its SIMD) fed by 4 A + 4 B frags. Hybrid feed splits the bytes:
//     A via LDS (stage 16KB + read 32KB per BK=32 tile = 47 B/cy < 85)
//     B direct global->VGPR from L2 (32KB + 16KB A-DMA = 47 B/cy < 56)
//   Both ports under budget => MFMA pipe becomes binding for the first time.
// Geometry: 256x256 block, 4 waves (2x2), per-wave 128x128, BK=32,
// LDS = A only, 2x16KB. ~380 VGPR -> launch_bounds(256,1), 1 wave/SIMD
// (OK: 16-MFMA bursts hide the 4 ds_reads; compiler's counted waits).
// Issue order per tile: B loads (oldest) -> STAGE_A(kt+1) -> compute
// (compiler waits b via vmcnt(4), staging stays in flight) -> vmcnt(0),
// barrier.
// Stripe layout (verified R13/R15): unit u=(r>>5)*(K>>4)+(k>>4), 512 els;
// lane l of a unit = row l&31, k-els (l>>5)*8..+8 = exact MFMA fragment;
// GLD16/dwordx4 of one unit: 1KB contiguous, 0-conflict.
// Accumulation order identical to R15-R19 -> absmax must stay 0.00048828.
// ---------------------------------------------------------------------------

typedef short shortx8 __attribute__((ext_vector_type(8)));
typedef short shortx4 __attribute__((ext_vector_type(4)));
typedef float floatx16 __attribute__((ext_vector_type(16)));
typedef __attribute__((address_space(3))) void lds_void_t;
typedef __attribute__((address_space(1))) const void gmem_void_t;

#define GLD16(gp, lp) \
    __builtin_amdgcn_global_load_lds((gmem_void_t*)(gp), (lds_void_t*)(lp), 16, 0, 0)

#define MODE_PROJ 0   // z=0,1: C=bf16(A B^T) striped;  z=2: Vt striped
#define MODE_EXP  1   // C = bf16(exp(alpha A B^T)) striped, rowsum += exp
#define MODE_DIV  2   // C = fp32(A B^T) / rowsum[row], row-major

// C[M,N] = f(A[M,K] @ B[N,K]^T). A,B striped (k-dim = K). z-batched.
// 256x256 tile, BK=32, 4 waves: wm=(w>>1)*128, wn=(w&1)*128, acc[4][4].
template <int MODE>
__global__ __launch_bounds__(256, 1) void mfma_gemm_abt(
    const __hip_bfloat16* __restrict__ A, const __hip_bfloat16* __restrict__ B,
    void* __restrict__ Cv, float* __restrict__ rowsum,
    __hip_bfloat16* __restrict__ Vt,
    int M, int N, int K, long sA, long sB, long sC, float alpha)
{
    __shared__ __hip_bfloat16 lds[2 * 8192];    // A only: 2 x 16KB

    using CT = std::conditional_t<MODE == MODE_DIV, float, __hip_bfloat16>;

    const int z = blockIdx.z;
    A += (long)z * sA;
    B += (long)z * sB;
    CT* C = (CT*)Cv + (long)z * sC;

    const int t     = threadIdx.x;          // 0..255
    const int wave  = t >> 6;               // 0..3
    const int lane  = t & 63;
    const int m0    = blockIdx.x * 256;
    const int n0    = blockIdx.y * 256;
    const int wm    = (wave >> 1) * 128;    // 0,128
    const int wn    = (wave & 1) * 128;     // 0,128
    const int lrow  = lane & 31;            // col of C
    const int lhalf = lane >> 5;            // +4 rows in C

    // A staging: wave w owns rgroups 2w, 2w+1 (4 GLD16/tile).
    const long KU   = (long)(K >> 4);       // k-units per row-group
    const long aSrc = (long)((m0 >> 5) + 2 * wave) * KU * 512 + lane * 8;
    const int  dA   = wave * 2048;          // LDS slots (4w+q)*512

    // A fragment reads: rg = (w>>1)*4 + i, slot (rg*2+s)*512 (0-conflict).
    const int raB = (wave >> 1) * 4096 + lane * 8;   // + i*1024 + s*512

    // B direct: wave col (w&1) owns rgroups (n0>>5)+(w&1)*4 + j.
    const __hip_bfloat16* pB0 =
        B + (long)((n0 >> 5) + (wave & 1) * 4 + 0) * KU * 512 + lane * 8;
    const __hip_bfloat16* pB1 =
        B + (long)((n0 >> 5) + (wave & 1) * 4 + 1) * KU * 512 + lane * 8;
    const __hip_bfloat16* pB2 =
        B + (long)((n0 >> 5) + (wave & 1) * 4 + 2) * KU * 512 + lane * 8;
    const __hip_bfloat16* pB3 =
        B + (long)((n0 >> 5) + (wave & 1) * 4 + 3) * KU * 512 + lane * 8;

#define STAGE_A(bo_, kt_) do {                                                \
        _Pragma("unroll")                                                     \
        for (int q = 0; q < 2; ++q) {                                         \
            GLD16(A + aSrc + (long)(2 * (kt_) + q) * 512,                     \
                  lds + (bo_) + dA + q * 512);                                \
            GLD16(A + aSrc + (KU + 2 * (kt_) + q) * 512,                      \
                  lds + (bo_) + dA + 1024 + q * 512);                         \
        }                                                                     \
    } while (0)

    floatx16 acc[4][4] = {};
    const int KT = K >> 5;

    STAGE_A(0, 0);                                // prologue: tile 0 -> buf 0
    asm volatile("s_waitcnt vmcnt(0)" ::: "memory");
    __builtin_amdgcn_s_barrier();

    for (int kt = 0; kt < KT; ++kt) {
        // B loads for this tile, both k-steps (oldest in vmem queue)
        const long kb = (long)(2 * kt) * 512;
        shortx8 b0[4], b1[4];
        b0[0] = *(const shortx8*)(pB0 + kb);
        b0[1] = *(const shortx8*)(pB1 + kb);
        b0[2] = *(const shortx8*)(pB2 + kb);
        b0[3] = *(const shortx8*)(pB3 + kb);
        b1[0] = *(const shortx8*)(pB0 + kb + 512);
        b1[1] = *(const shortx8*)(pB1 + kb + 512);
        b1[2] = *(const shortx8*)(pB2 + kb + 512);
        b1[3] = *(const shortx8*)(pB3 + kb + 512);

        if (kt + 1 < KT)                          // staging stays in flight
            STAGE_A(((kt + 1) & 1) * 8192, kt + 1);

        const __hip_bfloat16* Ls = lds + (kt & 1) * 8192;

        #pragma unroll
        for (int s = 0; s < 2; ++s) {             // two K=16 steps
            shortx8 a[4];
            #pragma unroll
            for (int i = 0; i < 4; ++i)
                a[i] = *(const shortx8*)(Ls + raB + i * 1024 + s * 512);
            __builtin_amdgcn_s_setprio(1);
            #pragma unroll
            for (int i = 0; i < 4; ++i)
                #pragma unroll
                for (int j = 0; j < 4; ++j)
                    acc[i][j] = __builtin_amdgcn_mfma_f32_32x32x16_bf16(
                        a[i], (s == 0) ? b0[j] : b1[j], acc[i][j], 0, 0, 0);
            __builtin_amdgcn_s_setprio(0);
        }
        // own STAGE_A(kt+1) done; all buf^1 readers retired before barrier
        asm volatile("s_waitcnt vmcnt(0)" ::: "memory");
        __builtin_amdgcn_s_barrier();
    }
#undef STAGE_A

    // stripe store index for C striped with k-dim = N
    auto sidx = [&](int row, int col) -> long {
        return ((long)(row >> 5) * (N >> 4) + (col >> 4)) * 512
             + ((row & 31) + 32 * ((col >> 3) & 1)) * 8 + (col & 7);
    };

    // C/D layout (verified m74/m101): col = lane&31,
    // row = (reg&3) + 8*(reg>>2) + 4*(lane>>5),  reg in [0,16)
    if constexpr (MODE == MODE_PROJ) {
        if (z == 2) {
            // V -> Vt striped over (rows=d 1024, k=t 2048)
            const int bz   = m0 >> 11;          // batch = row / T
            const long bo2 = (long)bz * N * 2048;
            #pragma unroll
            for (int i = 0; i < 4; ++i)
                #pragma unroll
                for (int j = 0; j < 4; ++j)
                    #pragma unroll
                    for (int g = 0; g < 4; ++g) {
                        const int t0 = (m0 + wm + 32 * i + g * 8 + 4 * lhalf) & 2047;
                        const int d  = n0 + wn + 32 * j + lrow;
                        shortx4 pk;
                        #pragma unroll
                        for (int r = 0; r < 4; ++r) {
                            __hip_bfloat16 hb = __float2bfloat16(acc[i][j][4 * g + r]);
                            pk[r] = *(short*)&hb;
                        }
                        const long idx = bo2
                            + ((long)(d >> 5) * 128 + (t0 >> 4)) * 512
                            + ((d & 31) + 32 * ((t0 >> 3) & 1)) * 8 + (t0 & 7);
                        *(shortx4*)(Vt + idx) = pk;   // 4 consecutive t els
                    }
        } else {
            #pragma unroll
            for (int i = 0; i < 4; ++i)
                #pragma unroll
                for (int j = 0; j < 4; ++j)
                    #pragma unroll
                    for (int g = 0; g < 4; ++g)
                        #pragma unroll
                        for (int r = 0; r < 4; ++r) {
                            const int row = m0 + wm + 32 * i + g * 8 + 4 * lhalf + r;
                            const int col = n0 + wn + 32 * j + lrow;
                            C[sidx(row, col)] = __float2bfloat16(acc[i][j][4 * g + r]);
                        }
        }
    } else if constexpr (MODE == MODE_EXP) {
        #pragma unroll
        for (int i = 0; i < 4; ++i) {
            float rs[16];
            #pragma unroll
            for (int reg = 0; reg < 16; ++reg) rs[reg] = 0.0f;
            #pragma unroll
            for (int j = 0; j < 4; ++j)
                #pragma unroll
                for (int g = 0; g < 4; ++g)
                    #pragma unroll
                    for (int r = 0; r < 4; ++r) {
                        const int row = m0 + wm + 32 * i + g * 8 + 4 * lhalf + r;
                        const int col = n0 + wn + 32 * j + lrow;
                        const float e = __expf(acc[i][j][4 * g + r] * alpha);
                        rs[4 * g + r] += e;
                        C[sidx(row, col)] = __float2bfloat16(e);
                    }
            #pragma unroll
            for (int reg = 0; reg < 16; ++reg) {
                float v = rs[reg];
                v += __shfl_xor(v, 1);
                v += __shfl_xor(v, 2);
                v += __shfl_xor(v, 4);
                v += __shfl_xor(v, 8);
                v += __shfl_xor(v, 16);
                if (lrow == 0) {
                    const long row = m0 + wm + 32 * i + (reg >> 2) * 8 + 4 * lhalf + (reg & 3);
                    atomicAdd(&rowsum[(long)z * M + row], v);
                }
            }
        }
    } else {  // MODE_DIV: out row-major fp32
        #pragma unroll
        for (int i = 0; i < 4; ++i) {
            float inv[16];
            #pragma unroll
            for (int g = 0; g < 4; ++g)
                #pragma unroll
                for (int r = 0; r < 4; ++r) {
                    const long row = m0 + wm + 32 * i + g * 8 + 4 * lhalf + r;
                    inv[4 * g + r] = 1.0f / rowsum[(long)z * M + row];
                }
            #pragma unroll
            for (int j = 0; j < 4; ++j)
                #pragma unroll
                for (int g = 0; g < 4; ++g)
                    #pragma unroll
                    for (int r = 0; r < 4; ++r) {
                        const long row = m0 + wm + 32 * i + g * 8 + 4 * lhalf + r;
                        const long col = n0 + wn + 32 * j + lrow;
                        C[row * N + col] = acc[i][j][4 * g + r] * inv[4 * g + r];
                    }
        }
    }
}

// prep: cast x / Wq|Wk|Wv fp32->bf16 into stripe layout via LDS transpose.
// Block = one 32-row group x K=1024: coalesced float4 reads -> striped LDS
// image (64KB) -> 64KB CONTIGUOUS global write. Blocks 0..255: xb;
// 256..351: Wb. Blocks 0..31 also zero rowsum.
__global__ __launch_bounds__(256) void prep(
    const float* __restrict__ x,
    const float* __restrict__ W0, const float* __restrict__ W1,
    const float* __restrict__ W2,
    __hip_bfloat16* __restrict__ xb, __hip_bfloat16* __restrict__ Wb,
    float* __restrict__ rowsum)
{
    __shared__ __hip_bfloat16 sb[32768];    // 64KB striped image

    const int b  = blockIdx.x;
    const int tt = threadIdx.x;             // 0..255

    if (b < 32) {
        float4 zz; zz.x = zz.y = zz.z = zz.w = 0.0f;
        ((float4*)rowsum)[b * 256 + tt] = zz;
    }

    const float* src;
    __hip_bfloat16* dst;
    if (b < 256) {
        src = x + (long)b * 32 * 1024;
        dst = xb + (long)b * 32768;
    } else {
        const int w  = (b - 256) >> 5;
        const int rg = (b - 256) & 31;
        src = ((w == 0) ? W0 : (w == 1) ? W1 : W2) + (long)rg * 32 * 1024;
        dst = Wb + (long)w * 1048576 + (long)rg * 32768;
    }

    #pragma unroll
    for (int it = 0; it < 32; ++it) {
        const int idx4 = it * 256 + tt;         // float4 index in row-major
        const float4 f = ((const float4*)src)[idx4];
        const int row = idx4 >> 8;              // 256 float4 per row
        const int k0  = (idx4 & 255) << 2;
        const int p   = ((row & 31) + 32 * ((k0 >> 3) & 1)) * 8 + (k0 & 7);
        shortx4 pk;
        __hip_bfloat16 h0 = __float2bfloat16(f.x); pk[0] = *(short*)&h0;
        __hip_bfloat16 h1 = __float2bfloat16(f.y); pk[1] = *(short*)&h1;
        __hip_bfloat16 h2 = __float2bfloat16(f.z); pk[2] = *(short*)&h2;
        __hip_bfloat16 h3 = __float2bfloat16(f.w); pk[3] = *(short*)&h3;
        *(shortx4*)(sb + (k0 >> 4) * 512 + p) = pk;
    }
    __syncthreads();

    #pragma unroll
    for (int ot = 0; ot < 16; ++ot) {
        const int off = ot * 2048 + tt * 8;
        *(shortx8*)(dst + off) = *(const shortx8*)(sb + off);
    }
}

extern "C" void kernel_launch(void* const* d_in, const int* in_sizes, int n_in,
                              void* d_out, int out_size, void* d_ws, size_t ws_size,
                              hipStream_t stream)
{
    constexpr int  Bb = 4, T = 2048, D = 1024;
    constexpr int  M  = Bb * T;                 // 8192
    constexpr long TD = (long)T * D;            // 2,097,152
    constexpr long TT = (long)T * T;            // 4,194,304
    constexpr long MD = (long)M * D;            // 8,388,608

    const float* x  = (const float*)d_in[0];
    const float* Wq = (const float*)d_in[1];
    const float* Wk = (const float*)d_in[2];
    const float* Wv = (const float*)d_in[3];
    float* out = (float*)d_out;

    // workspace: Q|K|Vt (bf16 16MB each) | P (bf16 33.6MB) | xb (16MB)
    //            | Wb (6MB) | rowsum (32KB)   -> ~104 MB  (all striped)
    __hip_bfloat16* Q  = (__hip_bfloat16*)d_ws;
    __hip_bfloat16* Kb = Q + MD;
    __hip_bfloat16* Vt = Kb + MD;
    __hip_bfloat16* P  = Vt + MD;
    __hip_bfloat16* xb = P + (long)Bb * TT;
    __hip_bfloat16* Wb = xb + MD;
    float*     rowsum  = (float*)(Wb + 3L * D * D);

    prep<<<dim3(352), dim3(256), 0, stream>>>(x, Wq, Wk, Wv, xb, Wb, rowsum);

    dim3 blk(256);

    // projections: z=0 -> Q, z=1 -> K, z=2 -> Vt (striped)
    mfma_gemm_abt<MODE_PROJ><<<dim3(M / 256, D / 256, 3), blk, 0, stream>>>(
        xb, Wb, Q, nullptr, Vt, M, D, D, 0, (long)D * D, MD, 1.0f);

    // P = exp(Q K^T / 32) bf16 striped, rowsum via atomics
    mfma_gemm_abt<MODE_EXP><<<dim3(T / 256, T / 256, Bb), blk, 0, stream>>>(
        Q, Kb, P, rowsum, nullptr, T, T, D, TD, TD, TT, 0.03125f);

    // out = (P @ Vt^T) / rowsum[row]  (row-major fp32 output)
    mfma_gemm_abt<MODE_DIV><<<dim3(T / 256, D / 256, Bb), blk, 0, stream>>>(
        P, Vt, out, rowsum, nullptr, T, D, T, TT, TD, TD, 1.0f);

    (void)in_sizes; (void)n_in; (void)out_size; (void)ws_size;
}

// Round 11
// 256.939 us; speedup vs baseline: 1.2460x; 1.2460x over previous
//
#include <hip/hip_runtime.h>
#include <hip/hip_bf16.h>
#include <math.h>
#include <type_traits>

// ---------------------------------------------------------------------------
// SelfAttention B=4,T=2048,D=1024 fp32 in/out.
// Round 21: corrected m201-faithful phase pipeline (4 phases / BK=64 tile).
//   R20: acc[4][4] spilled (VGPR 256 cap) -> retreat to acc[4][2].
//   R13-R20 synthesis: no port >50%; wall = per-tile dep chain; only
//   concurrent streams fill it (proj@3blk 537cy/tile vs div@1blk 2400).
//   m201 supplies intra-block overlap via phase split; R17's port failed
//   from sched_barrier(0) pins (m141) + 3 barriers/phase + bad vmcnt.
//   This port: per phase {6 ds_reads | 2 GLD16 | barrier | lgkmcnt(0) |
//   setprio(1) 8 MFMA setprio(0) | barrier}; NO sched_barrier; counted
//   vmcnt ONCE per tile before phase-3 closing barrier (wait-then-barrier
//   = cross-wave DMA visibility): vmcnt(6) steady (= 3 pairs in flight),
//   vmcnt(0) tail only. Issue schedule: p0 -> t+1 k3 (other buf);
//   p1-3 -> t+2 k(p-1) (current buf slots sealed by prior phase barrier).
//   Queue check: at each validation the 8 oldest loads = next tile's.
// Geometry: proj/exp BN=256: 512thr/8 waves, wave-tile 128x64, acc[4][2],
// LDS 2x64KB. div BN=128: acc[2][2], LDS 2x48KB, waves>=4 stage A only
// (their vmcnt = 3). Stripe layout / staging / epilogues / K-order
// unchanged (verified R15-R17) -> absmax must stay 0.0004882812.
// ---------------------------------------------------------------------------

typedef short shortx8 __attribute__((ext_vector_type(8)));
typedef short shortx4 __attribute__((ext_vector_type(4)));
typedef float floatx16 __attribute__((ext_vector_type(16)));
typedef __attribute__((address_space(3))) void lds_void_t;
typedef __attribute__((address_space(1))) const void gmem_void_t;

#define GLD16(gp, lp) \
    __builtin_amdgcn_global_load_lds((gmem_void_t*)(gp), (lds_void_t*)(lp), 16, 0, 0)

#define MODE_PROJ 0   // z=0,1: C=bf16(A B^T) striped;  z=2: Vt striped
#define MODE_EXP  1   // C = bf16(exp(alpha A B^T)) striped, rowsum += exp
#define MODE_DIV  2   // C = fp32(A B^T) / rowsum[row], row-major

// C[M,N] = f(A[M,K] @ B[N,K]^T). A,B striped (k-dim = K). z-batched.
// BK=64 (4 k-units), 512 thr / 8 waves.
// BN=256: wm=(w>>2)*128, wn=(w&3)*64, acc[4][2]. BN=128: wm=(w>>1)*64,
// wn=(w&1)*64, acc[2][2]. LDS buffer: A 8rg x 4ku units at (rg*4+ku)*512
// (16384 els); B at 16384 + (rg*4+ku)*512 (8 or 4 rgs).
template <int MODE, int BN>
__global__ __launch_bounds__(512, 1) void mfma_gemm_abt(
    const __hip_bfloat16* __restrict__ A, const __hip_bfloat16* __restrict__ B,
    void* __restrict__ Cv, float* __restrict__ rowsum,
    __hip_bfloat16* __restrict__ Vt,
    int M, int N, int K, long sA, long sB, long sC, float alpha)
{
    constexpr int MI   = (BN == 256) ? 4 : 2;
    constexpr int BUFE = (BN == 256) ? 32768 : 24576;   // els per buffer
    __shared__ __hip_bfloat16 lds[2 * BUFE];            // 128KB / 96KB

    using CT = std::conditional_t<MODE == MODE_DIV, float, __hip_bfloat16>;

    const int z = blockIdx.z;
    A += (long)z * sA;
    B += (long)z * sB;
    CT* C = (CT*)Cv + (long)z * sC;

    const int t     = threadIdx.x;          // 0..511
    const int wave  = t >> 6;               // 0..7
    const int lane  = t & 63;
    const int m0    = blockIdx.x * 256;
    const int n0    = blockIdx.y * BN;
    const int wm    = (BN == 256) ? (wave >> 2) * 128 : (wave >> 1) * 64;
    const int wn    = (BN == 256) ? (wave & 3) * 64   : (wave & 1) * 64;
    const int lrow  = lane & 31;            // col of C
    const int lhalf = lane >> 5;            // +4 rows in C

    // staging: wave w owns A rg=w; B rg=w (BN=256) or rg=w&3, waves<4 only.
    const long KU   = (long)(K >> 4);
    const long aSrc = (long)((m0 >> 5) + wave) * KU * 512 + lane * 8;
    const long bSrc = (long)((n0 >> 5) + ((BN == 256) ? wave : (wave & 3)))
                      * KU * 512 + lane * 8;
    const int  dAb  = wave * 2048;          // A slots (w*4+ku)*512
    const int  dBb  = 16384 + ((BN == 256) ? wave : (wave & 3)) * 2048;
    const bool stB  = (BN == 256) || (wave < 4);

    // fragment read bases: + i*2048 + p*512 (A), + j*2048 + p*512 (B)
    const int raB = ((BN == 256) ? (wave >> 2) * 8192 : (wave >> 1) * 4096)
                    + lane * 8;
    const int rbB = 16384
                    + ((BN == 256) ? (wave & 3) * 4096 : (wave & 1) * 4096)
                    + lane * 8;

#define SPAIR(bo_, t_, ku_) do {                                              \
        GLD16(A + aSrc + (long)(4 * (t_) + (ku_)) * 512,                      \
              lds + (bo_) + dAb + (ku_) * 512);                               \
        if (stB)                                                              \
            GLD16(B + bSrc + (long)(4 * (t_) + (ku_)) * 512,                  \
                  lds + (bo_) + dBb + (ku_) * 512);                           \
    } while (0)

    floatx16 acc[MI][2] = {};
    const int KT = K >> 6;                  // 16 (K=1024) or 32 (K=2048)

    // prologue: tile 0 fully, tile 1 ksteps 0..2 (k3 issued at t0.p0)
    #pragma unroll
    for (int ku = 0; ku < 4; ++ku) SPAIR(0, 0, ku);
    #pragma unroll
    for (int ku = 0; ku < 3; ++ku) SPAIR(BUFE, 1, ku);
    // validate tile 0 for all waves: own-wait then barrier
    if (stB) asm volatile("s_waitcnt vmcnt(6)" ::: "memory");
    else     asm volatile("s_waitcnt vmcnt(3)" ::: "memory");
    __builtin_amdgcn_s_barrier();

    for (int kt = 0; kt < KT; ++kt) {
        const int bo = (kt & 1) ? BUFE : 0;
        const int bn = bo ^ BUFE;
        const __hip_bfloat16* Ls = lds + bo;

        #pragma unroll
        for (int p = 0; p < 4; ++p) {
            // --- ds_read fragments for kstep p (data valid: tile kt was
            //     validated by the wait+barrier closing tile kt-1)
            shortx8 a[MI], b[2];
            #pragma unroll
            for (int i = 0; i < MI; ++i)
                a[i] = *(const shortx8*)(Ls + raB + i * 2048 + p * 512);
            #pragma unroll
            for (int j = 0; j < 2; ++j)
                b[j] = *(const shortx8*)(Ls + rbB + j * 2048 + p * 512);

            // --- staging issues (WAR sealed by the previous phase's
            //     closing barrier; targets never collide with live reads)
            if (p == 0) {
                if (kt + 1 < KT) SPAIR(bn, kt + 1, 3);
            } else {
                if (kt + 2 < KT) SPAIR(bo, kt + 2, p - 1);
            }

            __builtin_amdgcn_s_barrier();
            asm volatile("s_waitcnt lgkmcnt(0)" ::: "memory");
            __builtin_amdgcn_s_setprio(1);
            #pragma unroll
            for (int i = 0; i < MI; ++i)
                #pragma unroll
                for (int j = 0; j < 2; ++j)
                    acc[i][j] = __builtin_amdgcn_mfma_f32_32x32x16_bf16(
                        a[i], b[j], acc[i][j], 0, 0, 0);
            __builtin_amdgcn_s_setprio(0);
            if (p == 3 && kt + 1 < KT) {
                // validate tile kt+1: 8 oldest outstanding loads are its 4
                // pairs; 3 pairs (kt+2) may stay in flight.
                if (kt + 2 < KT) {
                    if (stB) asm volatile("s_waitcnt vmcnt(6)" ::: "memory");
                    else     asm volatile("s_waitcnt vmcnt(3)" ::: "memory");
                } else {
                    asm volatile("s_waitcnt vmcnt(0)" ::: "memory");
                }
            }
            __builtin_amdgcn_s_barrier();
        }
    }
#undef SPAIR

    // stripe store index for C striped with k-dim = N
    auto sidx = [&](int row, int col) -> long {
        return ((long)(row >> 5) * (N >> 4) + (col >> 4)) * 512
             + ((row & 31) + 32 * ((col >> 3) & 1)) * 8 + (col & 7);
    };

    // C/D layout (verified m74/m101): col = lane&31,
    // row = (reg&3) + 8*(reg>>2) + 4*(lane>>5),  reg in [0,16)
    if constexpr (MODE == MODE_PROJ) {
        if (z == 2) {
            // V -> Vt striped over (rows=d 1024, k=t 2048)
            const int bz   = m0 >> 11;          // batch = row / T
            const long bo2 = (long)bz * N * 2048;
            #pragma unroll
            for (int i = 0; i < MI; ++i)
                #pragma unroll
                for (int j = 0; j < 2; ++j)
                    #pragma unroll
                    for (int g = 0; g < 4; ++g) {
                        const int t0 = (m0 + wm + 32 * i + g * 8 + 4 * lhalf) & 2047;
                        const int d  = n0 + wn + 32 * j + lrow;
                        shortx4 pk;
                        #pragma unroll
                        for (int r = 0; r < 4; ++r) {
                            __hip_bfloat16 hb = __float2bfloat16(acc[i][j][4 * g + r]);
                            pk[r] = *(short*)&hb;
                        }
                        const long idx = bo2
                            + ((long)(d >> 5) * 128 + (t0 >> 4)) * 512
                            + ((d & 31) + 32 * ((t0 >> 3) & 1)) * 8 + (t0 & 7);
                        *(shortx4*)(Vt + idx) = pk;   // 4 consecutive t els
                    }
        } else {
            #pragma unroll
            for (int i = 0; i < MI; ++i)
                #pragma unroll
                for (int j = 0; j < 2; ++j)
                    #pragma unroll
                    for (int g = 0; g < 4; ++g)
                        #pragma unroll
                        for (int r = 0; r < 4; ++r) {
                            const int row = m0 + wm + 32 * i + g * 8 + 4 * lhalf + r;
                            const int col = n0 + wn + 32 * j + lrow;
                            C[sidx(row, col)] = __float2bfloat16(acc[i][j][4 * g + r]);
                        }
        }
    } else if constexpr (MODE == MODE_EXP) {
        #pragma unroll
        for (int i = 0; i < MI; ++i) {
            float rs[16];
            #pragma unroll
            for (int reg = 0; reg < 16; ++reg) rs[reg] = 0.0f;
            #pragma unroll
            for (int j = 0; j < 2; ++j)
                #pragma unroll
                for (int g = 0; g < 4; ++g)
                    #pragma unroll
                    for (int r = 0; r < 4; ++r) {
                        const int row = m0 + wm + 32 * i + g * 8 + 4 * lhalf + r;
                        const int col = n0 + wn + 32 * j + lrow;
                        const float e = __expf(acc[i][j][4 * g + r] * alpha);
                        rs[4 * g + r] += e;
                        C[sidx(row, col)] = __float2bfloat16(e);
                    }
            #pragma unroll
            for (int reg = 0; reg < 16; ++reg) {
                float v = rs[reg];
                v += __shfl_xor(v, 1);
                v += __shfl_xor(v, 2);
                v += __shfl_xor(v, 4);
                v += __shfl_xor(v, 8);
                v += __shfl_xor(v, 16);
                if (lrow == 0) {
                    const long row = m0 + wm + 32 * i + (reg >> 2) * 8 + 4 * lhalf + (reg & 3);
                    atomicAdd(&rowsum[(long)z * M + row], v);
                }
            }
        }
    } else {  // MODE_DIV: out row-major fp32
        #pragma unroll
        for (int i = 0; i < MI; ++i) {
            float inv[16];
            #pragma unroll
            for (int g = 0; g < 4; ++g)
                #pragma unroll
                for (int r = 0; r < 4; ++r) {
                    const long row = m0 + wm + 32 * i + g * 8 + 4 * lhalf + r;
                    inv[4 * g + r] = 1.0f / rowsum[(long)z * M + row];
                }
            #pragma unroll
            for (int j = 0; j < 2; ++j)
                #pragma unroll
                for (int g = 0; g < 4; ++g)
                    #pragma unroll
                    for (int r = 0; r < 4; ++r) {
                        const long row = m0 + wm + 32 * i + g * 8 + 4 * lhalf + r;
                        const long col = n0 + wn + 32 * j + lrow;
                        C[row * N + col] = acc[i][j][4 * g + r] * inv[4 * g + r];
                    }
        }
    }
}

// prep: cast x / Wq|Wk|Wv fp32->bf16 into stripe layout via LDS transpose.
// Block = one 32-row group x K=1024: coalesced float4 reads -> striped LDS
// image (64KB) -> 64KB CONTIGUOUS global write. Blocks 0..255: xb;
// 256..351: Wb. Blocks 0..31 also zero rowsum.
__global__ __launch_bounds__(256) void prep(
    const float* __restrict__ x,
    const float* __restrict__ W0, const float* __restrict__ W1,
    const float* __restrict__ W2,
    __hip_bfloat16* __restrict__ xb, __hip_bfloat16* __restrict__ Wb,
    float* __restrict__ rowsum)
{
    __shared__ __hip_bfloat16 sb[32768];    // 64KB striped image

    const int b  = blockIdx.x;
    const int tt = threadIdx.x;             // 0..255

    if (b < 32) {
        float4 zz; zz.x = zz.y = zz.z = zz.w = 0.0f;
        ((float4*)rowsum)[b * 256 + tt] = zz;
    }

    const float* src;
    __hip_bfloat16* dst;
    if (b < 256) {
        src = x + (long)b * 32 * 1024;
        dst = xb + (long)b * 32768;
    } else {
        const int w  = (b - 256) >> 5;
        const int rg = (b - 256) & 31;
        src = ((w == 0) ? W0 : (w == 1) ? W1 : W2) + (long)rg * 32 * 1024;
        dst = Wb + (long)w * 1048576 + (long)rg * 32768;
    }

    #pragma unroll
    for (int it = 0; it < 32; ++it) {
        const int idx4 = it * 256 + tt;         // float4 index in row-major
        const float4 f = ((const float4*)src)[idx4];
        const int row = idx4 >> 8;              // 256 float4 per row
        const int k0  = (idx4 & 255) << 2;
        const int p   = ((row & 31) + 32 * ((k0 >> 3) & 1)) * 8 + (k0 & 7);
        shortx4 pk;
        __hip_bfloat16 h0 = __float2bfloat16(f.x); pk[0] = *(short*)&h0;
        __hip_bfloat16 h1 = __float2bfloat16(f.y); pk[1] = *(short*)&h1;
        __hip_bfloat16 h2 = __float2bfloat16(f.z); pk[2] = *(short*)&h2;
        __hip_bfloat16 h3 = __float2bfloat16(f.w); pk[3] = *(short*)&h3;
        *(shortx4*)(sb + (k0 >> 4) * 512 + p) = pk;
    }
    __syncthreads();

    #pragma unroll
    for (int ot = 0; ot < 16; ++ot) {
        const int off = ot * 2048 + tt * 8;
        *(shortx8*)(dst + off) = *(const shortx8*)(sb + off);
    }
}

extern "C" void kernel_launch(void* const* d_in, const int* in_sizes, int n_in,
                              void* d_out, int out_size, void* d_ws, size_t ws_size,
                              hipStream_t stream)
{
    constexpr int  Bb = 4, T = 2048, D = 1024;
    constexpr int  M  = Bb * T;                 // 8192
    constexpr long TD = (long)T * D;            // 2,097,152
    constexpr long TT = (long)T * T;            // 4,194,304
    constexpr long MD = (long)M * D;            // 8,388,608

    const float* x  = (const float*)d_in[0];
    const float* Wq = (const float*)d_in[1];
    const float* Wk = (const float*)d_in[2];
    const float* Wv = (const float*)d_in[3];
    float* out = (float*)d_out;

    // workspace: Q|K|Vt (bf16 16MB each) | P (bf16 33.6MB) | xb (16MB)
    //            | Wb (6MB) | rowsum (32KB)   -> ~104 MB  (all striped)
    __hip_bfloat16* Q  = (__hip_bfloat16*)d_ws;
    __hip_bfloat16* Kb = Q + MD;
    __hip_bfloat16* Vt = Kb + MD;
    __hip_bfloat16* P  = Vt + MD;
    __hip_bfloat16* xb = P + (long)Bb * TT;
    __hip_bfloat16* Wb = xb + MD;
    float*     rowsum  = (float*)(Wb + 3L * D * D);

    prep<<<dim3(352), dim3(256), 0, stream>>>(x, Wq, Wk, Wv, xb, Wb, rowsum);

    dim3 blk(512);

    // projections: z=0 -> Q, z=1 -> K, z=2 -> Vt (striped)
    mfma_gemm_abt<MODE_PROJ, 256><<<dim3(M / 256, D / 256, 3), blk, 0, stream>>>(
        xb, Wb, Q, nullptr, Vt, M, D, D, 0, (long)D * D, MD, 1.0f);

    // P = exp(Q K^T / 32) bf16 striped, rowsum via atomics
    mfma_gemm_abt<MODE_EXP, 256><<<dim3(T / 256, T / 256, Bb), blk, 0, stream>>>(
        Q, Kb, P, rowsum, nullptr, T, T, D, TD, TD, TT, 0.03125f);

    // out = (P @ Vt^T) / rowsum[row]  (row-major fp32 output)
    mfma_gemm_abt<MODE_DIV, 128><<<dim3(T / 256, D / 128, Bb), blk, 0, stream>>>(
        P, Vt, out, rowsum, nullptr, T, D, T, TT, TD, TD, 1.0f);

    (void)in_sizes; (void)n_in; (void)out_size; (void)ws_size;
}